// Round 1
// baseline (1869.589 us; speedup 1.0000x reference)
//
#include <hip/hip_runtime.h>
#include <math.h>

#define B_ 32
#define C_ 32
#define N_ 512
#define T_ 480
#define EPS_ 1e-5f

static constexpr int    BCT  = B_ * C_ * T_;             // 491520
static constexpr long   BTT  = (long)B_ * T_ * T_;       // 7372800

// ---------------------------------------------------------------------------
// Kernel A: one pass over seq (1 GB) computing
//   tmp[b,c,t] = sum_n (sum_c' seq[b,c',n,t]*w1[c']) * w[n,c]   (= f1 @ w, transposed store)
//   f2 [b,c,t] = sum_n seq[b,c,n,t]*w2[n]
// Layouts [B,C,T] so the per-thread (one t each) atomics are lane-coalesced.
// Grid: (t-chunks=8, b=32, n-chunks=8), block=64 (one wave).
// 8 n-chunks (was 16): halves atomic traffic; 2048 waves = 8/CU still gives
// 64 KB of loads in flight per CU vs the ~9 KB needed to saturate HBM.
// ---------------------------------------------------------------------------
__global__ __launch_bounds__(64) void kA(const float* __restrict__ seq,
                                         const float* __restrict__ w1,
                                         const float* __restrict__ w2,
                                         const float* __restrict__ w,
                                         float* __restrict__ tmp,
                                         float* __restrict__ f2) {
    const int t  = blockIdx.x * 64 + threadIdx.x;
    const int b  = blockIdx.y;
    const int n0 = blockIdx.z * 64;
    if (t >= T_) return;

    float w1r[C_];
    #pragma unroll
    for (int c = 0; c < C_; ++c) w1r[c] = w1[c];   // uniform -> SGPRs

    float f2acc[C_] = {};
    float tmpacc[C_] = {};

    const float* base = seq + (size_t)b * C_ * N_ * T_ + t;
    for (int n = n0; n < n0 + 64; ++n) {
        const float w2n = w2[n];
        const float* p  = base + (size_t)n * T_;
        float s1 = 0.f;
        #pragma unroll
        for (int c = 0; c < C_; ++c) {
            float v = p[(size_t)c * N_ * T_];
            s1        += v * w1r[c];
            f2acc[c]  += v * w2n;
        }
        const float* wr = w + n * C_;   // uniform row -> scalar loads
        #pragma unroll
        for (int c = 0; c < C_; ++c) tmpacc[c] += s1 * wr[c];
    }

    #pragma unroll
    for (int c = 0; c < C_; ++c) {
        atomicAdd(&tmp[((size_t)b * C_ + c) * T_ + t], tmpacc[c]);
        atomicAdd(&f2 [((size_t)b * C_ + c) * T_ + t], f2acc[c]);
    }
}

// ---------------------------------------------------------------------------
// Kernel B: L[b,t,s] = sigmoid( sum_c tmp[b,c,t]*f2[b,c,s] + bias[t,s] )
// tmp reads are block-uniform (scalar); f2/bias coalesced on s.
// Grid: (2, T, B), block=256.
// ---------------------------------------------------------------------------
__global__ __launch_bounds__(256) void kB(const float* __restrict__ tmp,
                                          const float* __restrict__ f2,
                                          const float* __restrict__ bias,
                                          float* __restrict__ L) {
    const int s = blockIdx.x * 256 + threadIdx.x;
    const int t = blockIdx.y;
    const int b = blockIdx.z;
    if (s >= T_) return;
    float acc = bias[t * T_ + s];
    #pragma unroll
    for (int c = 0; c < C_; ++c)
        acc += tmp[((size_t)b * C_ + c) * T_ + t] * f2[((size_t)b * C_ + c) * T_ + s];
    const float sg = 1.f / (1.f + __expf(-acc));
    L[((size_t)b * T_ + t) * T_ + s] = sg;
}

// ---------------------------------------------------------------------------
// Kernel C: out[b,t,u] = sum_s v[t,s] * L[b,s,u]   (batched fp32 GEMM)
// 64x64 tile, BK=16, ONE WAVE per block, 8x8 micro-tile (1 B LDS-read/FMA,
// half the 4x4 version's LDS traffic -> LDS-bound time ~halves).
// Epilogue fuses the BN-stat column sums (sum, sumsq over rows) that used to
// be a separate 29.5 MB pass (old kD): shfl-reduce across ty, 16 atomics/blk.
// Grid: (u-tiles=8, t-tiles=8, b=32).
// ---------------------------------------------------------------------------
__global__ __launch_bounds__(64) void kC(const float* __restrict__ v,
                                         const float* __restrict__ L,
                                         float* __restrict__ out,
                                         float* __restrict__ sums) {
    __shared__ float Vs[16][68];   // [k][m], pad 68 keeps 2-way-max bank aliasing
    __shared__ float Ls[16][64];   // [k][n]

    const int b   = blockIdx.z;
    const int t0  = blockIdx.y * 64;
    const int u0  = blockIdx.x * 64;
    const int tid = threadIdx.x;
    const int tx  = tid & 7;        // u micro-index
    const int ty  = tid >> 3;       // t micro-index

    float acc[8][8] = {};
    const float* Lb = L + (size_t)b * T_ * T_;

    for (int k0 = 0; k0 < T_; k0 += 16) {
        // stage v tile transposed: Vs[k][m] = v[t0+m][k0+k]  (64 rows x 16 k)
        #pragma unroll
        for (int p = 0; p < 4; ++p) {
            const int i  = (tid >> 2) + p * 16;   // 0..63 (t row)
            const int j4 = (tid & 3) * 4;         // 0,4,8,12 (k col)
            float4 val = make_float4(0.f, 0.f, 0.f, 0.f);
            if (t0 + i < T_)
                val = *(const float4*)(v + (size_t)(t0 + i) * T_ + k0 + j4);
            Vs[j4 + 0][i] = val.x; Vs[j4 + 1][i] = val.y;
            Vs[j4 + 2][i] = val.z; Vs[j4 + 3][i] = val.w;
        }
        // stage L tile: Ls[k][n] = L[b][k0+k][u0+n]  (16 k x 64 u)
        #pragma unroll
        for (int p = 0; p < 4; ++p) {
            const int i  = (tid >> 4) + p * 4;    // 0..15 (k row)
            const int j4 = (tid & 15) * 4;        // 0..60 (u col)
            float4 val = make_float4(0.f, 0.f, 0.f, 0.f);
            if (u0 + j4 < T_)
                val = *(const float4*)(Lb + (size_t)(k0 + i) * T_ + u0 + j4);
            *(float4*)&Ls[i][j4] = val;
        }
        __syncthreads();   // single wave: effectively free
        #pragma unroll
        for (int kk = 0; kk < 16; ++kk) {
            float4 a0 = *(const float4*)&Vs[kk][ty * 8];
            float4 a1 = *(const float4*)&Vs[kk][ty * 8 + 4];
            float4 b0 = *(const float4*)&Ls[kk][tx * 8];
            float4 b1 = *(const float4*)&Ls[kk][tx * 8 + 4];
            const float aa[8] = {a0.x, a0.y, a0.z, a0.w, a1.x, a1.y, a1.z, a1.w};
            const float bb[8] = {b0.x, b0.y, b0.z, b0.w, b1.x, b1.y, b1.z, b1.w};
            #pragma unroll
            for (int i = 0; i < 8; ++i)
                #pragma unroll
                for (int j = 0; j < 8; ++j)
                    acc[i][j] += aa[i] * bb[j];
        }
        __syncthreads();
    }

    // store + per-column partials for BN stats (padded rows/cols are exact 0)
    float cs[8] = {}, cq[8] = {};
    #pragma unroll
    for (int i = 0; i < 8; ++i) {
        const int t = t0 + ty * 8 + i;
        const int u = u0 + tx * 8;
        if (t < T_ && u < T_) {
            *(float4*)(out + ((size_t)b * T_ + t) * T_ + u) =
                make_float4(acc[i][0], acc[i][1], acc[i][2], acc[i][3]);
            *(float4*)(out + ((size_t)b * T_ + t) * T_ + u + 4) =
                make_float4(acc[i][4], acc[i][5], acc[i][6], acc[i][7]);
        }
        #pragma unroll
        for (int j = 0; j < 8; ++j) {
            const float vv = acc[i][j];
            cs[j] += vv;
            cq[j] += vv * vv;
        }
    }
    // reduce across ty (lane bits 3..5), tx preserved
    #pragma unroll
    for (int off = 8; off < 64; off <<= 1) {
        #pragma unroll
        for (int j = 0; j < 8; ++j) {
            cs[j] += __shfl_xor(cs[j], off);
            cq[j] += __shfl_xor(cq[j], off);
        }
    }
    if (tid < 8) {
        #pragma unroll
        for (int j = 0; j < 8; ++j) {
            const int u = u0 + tid * 8 + j;
            if (u < T_) {
                atomicAdd(&sums[u],      cs[j]);
                atomicAdd(&sums[T_ + u], cq[j]);
            }
        }
    }
}

// ---------------------------------------------------------------------------
// Kernel E: in-place BN-normalize + masked row softmax. One wave per row.
// The mask (from _make_mask, T=480) is block-diagonal with row blocks
// [0,96) [96,192) [192,288) [288,480); in-block mask value is exactly 0 and
// out-of-block entries underflow to exactly 0.f after softmax (exp(-1e13)=0),
// matching the fp32 reference bit-for-bit. So: read/BN/exp only the in-block
// columns (96 or 192 of 480), write literal zeros elsewhere, never touch mask.
// Grid: 3840, block=256 (4 waves -> 4 rows).
// ---------------------------------------------------------------------------
__global__ __launch_bounds__(256) void kE(float* __restrict__ L2,
                                          const float* __restrict__ sums,
                                          const float* __restrict__ gamma,
                                          const float* __restrict__ beta) {
    const int lane = threadIdx.x & 63;
    const int wid  = threadIdx.x >> 6;
    const long r   = (long)blockIdx.x * 4 + wid;   // 0..15359
    const int t    = (int)(r % T_);

    int lo, hi;
    if      (t < 96)  { lo = 0;   hi = 96;  }
    else if (t < 192) { lo = 96;  hi = 192; }
    else if (t < 288) { lo = 192; hi = 288; }
    else              { lo = 288; hi = 480; }

    const float inv_cnt = 1.f / (float)(B_ * T_);

    float x[8];
    float m = -INFINITY;
    #pragma unroll
    for (int j = 0; j < 8; ++j) {
        const int u = lane + 64 * j;
        x[j] = -INFINITY;
        if (u >= lo && u < hi) {
            const float mean = sums[u] * inv_cnt;
            const float var  = sums[T_ + u] * inv_cnt - mean * mean;
            const float sc   = gamma[u] * rsqrtf(var + EPS_);
            const float val  = (L2[r * T_ + u] - mean) * sc + beta[u];
            x[j] = val;
            m = fmaxf(m, val);
        }
    }
    #pragma unroll
    for (int off = 32; off >= 1; off >>= 1) m = fmaxf(m, __shfl_xor(m, off));

    float ssum = 0.f;
    #pragma unroll
    for (int j = 0; j < 8; ++j) {
        const float e = (x[j] == -INFINITY) ? 0.f : __expf(x[j] - m);
        x[j] = e;
        ssum += e;
    }
    #pragma unroll
    for (int off = 32; off >= 1; off >>= 1) ssum += __shfl_xor(ssum, off);

    const float inv = 1.f / ssum;
    #pragma unroll
    for (int j = 0; j < 8; ++j) {
        const int u = lane + 64 * j;
        if (u < T_) L2[r * T_ + u] = x[j] * inv;   // out-of-block: exact 0.f
    }
}

// ---------------------------------------------------------------------------
extern "C" void kernel_launch(void* const* d_in, const int* in_sizes, int n_in,
                              void* d_out, int out_size, void* d_ws, size_t ws_size,
                              hipStream_t stream) {
    const float* seq   = (const float*)d_in[0];
    const float* w1    = (const float*)d_in[1];
    const float* w2    = (const float*)d_in[2];
    const float* w     = (const float*)d_in[3];
    const float* bias  = (const float*)d_in[4];
    const float* v     = (const float*)d_in[5];
    const float* gamma = (const float*)d_in[6];
    const float* beta  = (const float*)d_in[7];
    float* out = (float*)d_out;
    float* ws  = (float*)d_ws;

    float* tmp  = ws;                       // [B,C,T]
    float* f2   = ws + BCT;                 // [B,C,T]
    float* sums = ws + 2 * BCT;             // [2*T]
    float* L    = ws + 2 * BCT + 2 * T_;    // [B,T,T] sigmoid logits

    // zero the atomic accumulators (ws is poisoned 0xAA before every launch)
    hipMemsetAsync(ws, 0, (size_t)(2 * BCT + 2 * T_) * sizeof(float), stream);

    kA<<<dim3(8, 32, 8), 64, 0, stream>>>(seq, w1, w2, w, tmp, f2);
    kB<<<dim3(2, T_, B_), 256, 0, stream>>>(tmp, f2, bias, L);
    kC<<<dim3(8, 8, B_), 64, 0, stream>>>(v, L, out, sums);  // out = L2, + BN stats
    kE<<<3840, 256, 0, stream>>>(out, sums, gamma, beta);
}